// Round 2
// baseline (182.309 us; speedup 1.0000x reference)
//
#include <hip/hip_runtime.h>
#include <hip/hip_bf16.h>

typedef __attribute__((ext_vector_type(8))) short bf16x8;
typedef __attribute__((ext_vector_type(4))) float f32x4;

#define NB    4096
#define NLINK 33
#define NJ    32
#define KTOT  1024
#define CJ    128
#define BM    128
#define BK    64
#define NT    (KTOT / BK)   // 16 K-tiles

// Pre-converted, fragment-swizzled bf16 copy of W (8.4 MB), rebuilt every call.
// Layout: cell index ((j*32 + kt)*128 + c)*4 + q  holds bf16x8 of
// W[j][kt*32 + q*8 + e][c], e = 0..7  — exactly one dwordx4 per MFMA B-fragment.
__device__ short g_Wf[NJ * KTOT * CJ];

// round-to-nearest-even f32 -> bf16 (finite inputs)
static __device__ __forceinline__ short f2bf(float f) {
    unsigned u = __builtin_bit_cast(unsigned, f);
    unsigned r = u + 0x7FFFu + ((u >> 16) & 1u);
    return (short)(r >> 16);
}

__global__ __launch_bounds__(256) void conv_w(const float* __restrict__ W) {
    const int gid = blockIdx.x * 256 + threadIdx.x;   // == destination cell index
    const int q  = gid & 3;
    const int c  = (gid >> 2) & 127;
    const int kt = (gid >> 9) & 31;
    const int j  = gid >> 14;
    const float* src = W + ((size_t)j * KTOT + kt * 32 + q * 8) * CJ + c;
    bf16x8 v;
    #pragma unroll
    for (int e = 0; e < 8; ++e) v[e] = f2bf(src[(size_t)e * CJ]);
    reinterpret_cast<bf16x8*>(g_Wf)[gid] = v;
}

__global__ __launch_bounds__(512, 4) void joint_gemm(
    const float* __restrict__ link,
    const float* __restrict__ jf,
    const float* __restrict__ bias,
    const int*   __restrict__ child,
    float* __restrict__ out)
{
    // A tile, bf16, double-buffered. Row-major [row][cell], 8 cells (bf16x8) per
    // row (128B pitch), physical cell = logical_ks ^ (row & 7)  (XOR swizzle ->
    // balanced 8-phase b128 access on both write and fragment read).
    __shared__ short lA[2][BM * BK];   // 2 x 16 KB

    const int tid  = threadIdx.x;
    const int lane = tid & 63;
    const int wave = tid >> 6;     // 0..7
    const int wr   = wave >> 1;    // 0..3 : 32-row band
    const int wc   = wave & 1;     // 0..1 : 64-col band
    const int q    = lane >> 4;    // 0..3
    const int r    = lane & 15;    // 0..15
    const int xr   = r & 7;        // read-side swizzle key

    const int bx = blockIdx.x;
    const int j  = bx & 31;        // j-minor: round-robin XCD dispatch -> 4 joints/XCD
    const int mt = bx >> 5;
    const int rowbase = mt * BM;
    const int cidx = child[j];

    // ---- A staging mapping: thread tid handles row=tid>>2, 16 consecutive f32
    const int srow   = tid >> 2;    // 0..127
    const int squart = tid & 3;     // 0..3  (16-float quarter of the 64-float K window)
    const float* abase = link + ((size_t)(rowbase + srow) * NLINK + cidx) * KTOT + squart * 16;
    const int xw = srow & 7;                 // write-side swizzle key
    const int p0 = (squart * 2) ^ xw;        // physical cell of logical ks = squart*2
    const int p1 = p0 ^ 1;                   // physical cell of logical ks+1

    // ---- B fragments: direct from pre-swizzled global bf16 (L2-resident)
    const bf16x8* wb = reinterpret_cast<const bf16x8*>(g_Wf);
    const size_t bbase = ((size_t)j * 32 * 128 + wc * 64 + r) * 4 + q;

    f32x4  acc[2][4] = {};
    float4 fa4[4];           // raw f32 A prefetch (16 floats)
    bf16x8 Breg[2][4];       // B fragments for current tile

    auto loadA = [&](int t) {
        const float4* p = reinterpret_cast<const float4*>(abase + (size_t)t * BK);
        fa4[0] = p[0]; fa4[1] = p[1]; fa4[2] = p[2]; fa4[3] = p[3];
    };
    auto stageA = [&](int b) {
        const float* f = reinterpret_cast<const float*>(fa4);
        bf16x8 v0, v1;
        #pragma unroll
        for (int e = 0; e < 8; ++e) { v0[e] = f2bf(f[e]); v1[e] = f2bf(f[8 + e]); }
        bf16x8* Lw = reinterpret_cast<bf16x8*>(lA[b]) + srow * 8;
        Lw[p0] = v0;
        Lw[p1] = v1;
    };
    auto loadB = [&](int t) {
        #pragma unroll
        for (int kk = 0; kk < 2; ++kk)
            #pragma unroll
            for (int ni = 0; ni < 4; ++ni)
                Breg[kk][ni] = wb[bbase + (size_t)(t * 2 + kk) * 512 + ni * 64];
    };

    // ---- prologue
    loadA(0);
    loadB(0);
    stageA(0);
    loadA(1);
    __syncthreads();

    int cur = 0;
    for (int t = 0; t < NT; ++t) {
        if (t + 1 < NT) stageA(cur ^ 1);    // convert+write tile t+1 (regs loaded last iter)
        if (t + 2 < NT) loadA(t + 2);       // HBM loads 2 tiles ahead

        const bf16x8* Lr = reinterpret_cast<const bf16x8*>(lA[cur]);
        #pragma unroll
        for (int kk = 0; kk < 2; ++kk) {
            bf16x8 af[2];
            #pragma unroll
            for (int mi = 0; mi < 2; ++mi) {
                const int R = wr * 32 + mi * 16 + r;
                af[mi] = Lr[R * 8 + (((kk << 2) | q) ^ xr)];
            }
            #pragma unroll
            for (int mi = 0; mi < 2; ++mi)
                #pragma unroll
                for (int ni = 0; ni < 4; ++ni)
                    acc[mi][ni] = __builtin_amdgcn_mfma_f32_16x16x32_bf16(
                        af[mi], Breg[kk][ni], acc[mi][ni], 0, 0, 0);
        }

        if (t + 1 < NT) loadB(t + 1);       // L2 hits, in flight across the barrier
        __syncthreads();
        cur ^= 1;
    }

    // ---- epilogue: + bias + joint_feats
    float bv[4];
    #pragma unroll
    for (int ni = 0; ni < 4; ++ni) bv[ni] = bias[j * CJ + wc * 64 + ni * 16 + r];

    #pragma unroll
    for (int mi = 0; mi < 2; ++mi) {
        #pragma unroll
        for (int rr = 0; rr < 4; ++rr) {
            const int bg = rowbase + wr * 32 + mi * 16 + q * 4 + rr;
            const size_t ob = ((size_t)bg * NJ + j) * CJ;
            #pragma unroll
            for (int ni = 0; ni < 4; ++ni) {
                const int o = wc * 64 + ni * 16 + r;
                out[ob + o] = acc[mi][ni][rr] + bv[ni] + jf[ob + o];
            }
        }
    }
}

extern "C" void kernel_launch(void* const* d_in, const int* in_sizes, int n_in,
                              void* d_out, int out_size, void* d_ws, size_t ws_size,
                              hipStream_t stream) {
    (void)in_sizes; (void)n_in; (void)out_size; (void)d_ws; (void)ws_size;
    const float* link  = (const float*)d_in[0];
    const float* jfeat = (const float*)d_in[1];
    const float* W     = (const float*)d_in[2];
    const float* bias  = (const float*)d_in[3];
    const int*   child = (const int*)d_in[4];
    float* out = (float*)d_out;

    // W -> bf16, fragment-swizzled (8.4 MB, ~8 us; W is batch-independent)
    conv_w<<<dim3((NJ * KTOT * CJ / 8) / 256), dim3(256), 0, stream>>>(W);
    // grouped GEMM: 32 m-tiles x 32 joints, j-minor
    joint_gemm<<<dim3(NJ * (NB / BM)), dim3(512), 0, stream>>>(link, jfeat, bias, child, out);
}